// Round 2
// baseline (134.318 us; speedup 1.0000x reference)
//
#include <hip/hip_runtime.h>

// SimpleRPMGLoss: out = mean(smooth_l1(pred[:,:3], tgt[:,:3]))
//               + 100 * mean(acos(clip((sum(R(pred_e)*R(tgt_e)) - 1)/2)))
// B = 2,097,152 rows x 6 f32 each input. Memory-bound streaming reduction (~100 MB read).
// Fused single kernel: per-block partial -> agent-scope counter -> last block finishes.

constexpr int   B_ROWS  = 2097152;
constexpr int   NBLK    = 2048;             // 8 blocks/CU on 256 CUs
constexpr int   TPB     = 256;
constexpr int   NTHREAD = NBLK * TPB;       // 524288
constexpr int   NPAIRS  = B_ROWS / 2;       // 1048576 = NTHREAD * 2 exactly
constexpr float ANGLE_WEIGHT = 100.0f;
constexpr float EPS_F        = 1e-7f;

typedef float f32x4 __attribute__((ext_vector_type(4)));

__device__ inline float smooth_l1_term(float d) {
    float ad = fabsf(d);
    return ad < 1.0f ? 0.5f * d * d : ad - 0.5f;
}

__device__ inline void euler_xyz_mat(float a, float b, float c, float r[9]) {
    float sa, ca, sb, cb, sc, cc;
    __sincosf(a, &sa, &ca);
    __sincosf(b, &sb, &cb);
    __sincosf(c, &sc, &cc);
    r[0] = cb * cc;
    r[1] = cc * sa * sb - ca * sc;
    r[2] = sc * sa + ca * cc * sb;
    r[3] = cb * sc;
    r[4] = ca * cc + sa * sb * sc;
    r[5] = ca * sb * sc - cc * sa;
    r[6] = -sb;
    r[7] = cb * sa;
    r[8] = ca * cb;
}

__device__ inline void accum_row(float px, float py, float pz,
                                 float pa, float pb, float pc,
                                 float tx, float ty, float tz,
                                 float ta, float tb, float tc,
                                 float& trans_acc, float& rot_acc) {
    trans_acc += smooth_l1_term(px - tx) + smooth_l1_term(py - ty) + smooth_l1_term(pz - tz);
    float rp[9], rt[9];
    euler_xyz_mat(pa, pb, pc, rp);
    euler_xyz_mat(ta, tb, tc, rt);
    float tr = 0.0f;
#pragma unroll
    for (int i = 0; i < 9; ++i) tr = fmaf(rp[i], rt[i], tr);
    float cosang = fminf(fmaxf((tr - 1.0f) * 0.5f, -1.0f + EPS_F), 1.0f - EPS_F);
    rot_acc += acosf(cosang);
}

// One "pair" = 2 rows = 12 floats = three aligned float4 per input.
__device__ inline void accum_pair(const f32x4* __restrict__ pp,
                                  const f32x4* __restrict__ tp,
                                  float& trans_acc, float& rot_acc) {
    f32x4 p0 = __builtin_nontemporal_load(pp + 0);
    f32x4 p1 = __builtin_nontemporal_load(pp + 1);
    f32x4 p2 = __builtin_nontemporal_load(pp + 2);
    f32x4 t0 = __builtin_nontemporal_load(tp + 0);
    f32x4 t1 = __builtin_nontemporal_load(tp + 1);
    f32x4 t2 = __builtin_nontemporal_load(tp + 2);
    accum_row(p0[0], p0[1], p0[2], p0[3], p1[0], p1[1],
              t0[0], t0[1], t0[2], t0[3], t1[0], t1[1], trans_acc, rot_acc);
    accum_row(p1[2], p1[3], p2[0], p2[1], p2[2], p2[3],
              t1[2], t1[3], t2[0], t2[1], t2[2], t2[3], trans_acc, rot_acc);
}

__global__ __launch_bounds__(TPB) void rpmg_fused_kernel(const float* __restrict__ pred,
                                                         const float* __restrict__ tgt,
                                                         float2* __restrict__ partial,
                                                         unsigned int* __restrict__ counter,
                                                         float* __restrict__ out) {
    const int tid = blockIdx.x * TPB + threadIdx.x;
    const f32x4* pbase = reinterpret_cast<const f32x4*>(pred);
    const f32x4* tbase = reinterpret_cast<const f32x4*>(tgt);

    float trans_acc = 0.0f, rot_acc = 0.0f;
    // Exactly 2 pairs per thread, straightline so all 12 loads can issue early.
    accum_pair(pbase + (size_t)tid * 3,             tbase + (size_t)tid * 3,             trans_acc, rot_acc);
    accum_pair(pbase + (size_t)(tid + NTHREAD) * 3, tbase + (size_t)(tid + NTHREAD) * 3, trans_acc, rot_acc);

    // Block reduction.
#pragma unroll
    for (int off = 32; off > 0; off >>= 1) {
        trans_acc += __shfl_down(trans_acc, off, 64);
        rot_acc   += __shfl_down(rot_acc,   off, 64);
    }
    __shared__ float sa[TPB / 64], sb[TPB / 64];
    __shared__ int   s_last;
    const int wid  = threadIdx.x >> 6;
    const int lane = threadIdx.x & 63;
    if (lane == 0) { sa[wid] = trans_acc; sb[wid] = rot_acc; }
    __syncthreads();
    if (threadIdx.x == 0) {
        float ta = 0.0f, tb = 0.0f;
#pragma unroll
        for (int w = 0; w < TPB / 64; ++w) { ta += sa[w]; tb += sb[w]; }
        // Agent-scope stores: per-XCD L2s aren't coherent; the finisher block may
        // be on a different XCD and may hold stale lines from a previous replay.
        __hip_atomic_store(&partial[blockIdx.x].x, ta, __ATOMIC_RELAXED, __HIP_MEMORY_SCOPE_AGENT);
        __hip_atomic_store(&partial[blockIdx.x].y, tb, __ATOMIC_RELAXED, __HIP_MEMORY_SCOPE_AGENT);
        unsigned int old = __hip_atomic_fetch_add(counter, 1u, __ATOMIC_ACQ_REL, __HIP_MEMORY_SCOPE_AGENT);
        s_last = (old == (unsigned int)(NBLK - 1)) ? 1 : 0;
    }
    __syncthreads();

    if (s_last) {
        // Last block: deterministic fixed-order reduction of all partials.
        float ta = 0.0f, tb = 0.0f;
        for (int i = threadIdx.x; i < NBLK; i += TPB) {
            ta += __hip_atomic_load(&partial[i].x, __ATOMIC_RELAXED, __HIP_MEMORY_SCOPE_AGENT);
            tb += __hip_atomic_load(&partial[i].y, __ATOMIC_RELAXED, __HIP_MEMORY_SCOPE_AGENT);
        }
#pragma unroll
        for (int off = 32; off > 0; off >>= 1) {
            ta += __shfl_down(ta, off, 64);
            tb += __shfl_down(tb, off, 64);
        }
        __syncthreads();   // reuse sa/sb safely
        if (lane == 0) { sa[wid] = ta; sb[wid] = tb; }
        __syncthreads();
        if (threadIdx.x == 0) {
            float st = 0.0f, sr = 0.0f;
#pragma unroll
            for (int w = 0; w < TPB / 64; ++w) { st += sa[w]; sr += sb[w]; }
            out[0] = st / (3.0f * (float)B_ROWS) + ANGLE_WEIGHT * (sr / (float)B_ROWS);
        }
    }
}

extern "C" void kernel_launch(void* const* d_in, const int* in_sizes, int n_in,
                              void* d_out, int out_size, void* d_ws, size_t ws_size,
                              hipStream_t stream) {
    const float* pred = (const float*)d_in[0];
    const float* tgt  = (const float*)d_in[1];
    float* out        = (float*)d_out;

    float2*       partial = (float2*)d_ws;                                   // 16 KB
    unsigned int* counter = (unsigned int*)((char*)d_ws + NBLK * sizeof(float2));

    hipMemsetAsync(counter, 0, sizeof(unsigned int), stream);
    rpmg_fused_kernel<<<NBLK, TPB, 0, stream>>>(pred, tgt, partial, counter, out);
}

// Round 3
// 86.975 us; speedup vs baseline: 1.5443x; 1.5443x over previous
//
#include <hip/hip_runtime.h>

// SimpleRPMGLoss: out = mean(smooth_l1(pred[:,:3], tgt[:,:3]))
//               + 100 * mean(acos(clip((sum(R(pred_e)*R(tgt_e)) - 1)/2)))
// B = 2,097,152 rows x 6 f32 each input. Memory-bound streaming reduction (~100 MB read).
// Fused single kernel: per-block partial -> agent-scope counter -> last block finishes.
// NOTE: plain cached loads, NOT nontemporal — nt bypasses L2/L3 on gfx950 and
// turned the L3-resident replay workload into HBM-latency-bound (134 us, 567 GB/s).

constexpr int   B_ROWS  = 2097152;
constexpr int   NBLK    = 2048;             // 8 blocks/CU on 256 CUs
constexpr int   TPB     = 256;
constexpr int   NTHREAD = NBLK * TPB;       // 524288 threads; 2 row-pairs each
constexpr float ANGLE_WEIGHT = 100.0f;
constexpr float EPS_F        = 1e-7f;

typedef float f32x4 __attribute__((ext_vector_type(4)));

__device__ inline float smooth_l1_term(float d) {
    float ad = fabsf(d);
    return ad < 1.0f ? 0.5f * d * d : ad - 0.5f;
}

__device__ inline void euler_xyz_mat(float a, float b, float c, float r[9]) {
    float sa, ca, sb, cb, sc, cc;
    __sincosf(a, &sa, &ca);
    __sincosf(b, &sb, &cb);
    __sincosf(c, &sc, &cc);
    r[0] = cb * cc;
    r[1] = cc * sa * sb - ca * sc;
    r[2] = sc * sa + ca * cc * sb;
    r[3] = cb * sc;
    r[4] = ca * cc + sa * sb * sc;
    r[5] = ca * sb * sc - cc * sa;
    r[6] = -sb;
    r[7] = cb * sa;
    r[8] = ca * cb;
}

__device__ inline void accum_row(float px, float py, float pz,
                                 float pa, float pb, float pc,
                                 float tx, float ty, float tz,
                                 float ta, float tb, float tc,
                                 float& trans_acc, float& rot_acc) {
    trans_acc += smooth_l1_term(px - tx) + smooth_l1_term(py - ty) + smooth_l1_term(pz - tz);
    float rp[9], rt[9];
    euler_xyz_mat(pa, pb, pc, rp);
    euler_xyz_mat(ta, tb, tc, rt);
    float tr = 0.0f;
#pragma unroll
    for (int i = 0; i < 9; ++i) tr = fmaf(rp[i], rt[i], tr);
    float cosang = fminf(fmaxf((tr - 1.0f) * 0.5f, -1.0f + EPS_F), 1.0f - EPS_F);
    rot_acc += acosf(cosang);
}

// One "pair" = 2 rows = 12 floats = three aligned float4 per input. Plain cached loads.
__device__ inline void accum_pair(const f32x4* __restrict__ pp,
                                  const f32x4* __restrict__ tp,
                                  float& trans_acc, float& rot_acc) {
    f32x4 p0 = pp[0], p1 = pp[1], p2 = pp[2];
    f32x4 t0 = tp[0], t1 = tp[1], t2 = tp[2];
    accum_row(p0[0], p0[1], p0[2], p0[3], p1[0], p1[1],
              t0[0], t0[1], t0[2], t0[3], t1[0], t1[1], trans_acc, rot_acc);
    accum_row(p1[2], p1[3], p2[0], p2[1], p2[2], p2[3],
              t1[2], t1[3], t2[0], t2[1], t2[2], t2[3], trans_acc, rot_acc);
}

__global__ __launch_bounds__(TPB) void rpmg_fused_kernel(const float* __restrict__ pred,
                                                         const float* __restrict__ tgt,
                                                         float2* __restrict__ partial,
                                                         unsigned int* __restrict__ counter,
                                                         float* __restrict__ out) {
    const int tid = blockIdx.x * TPB + threadIdx.x;
    const f32x4* pbase = reinterpret_cast<const f32x4*>(pred);
    const f32x4* tbase = reinterpret_cast<const f32x4*>(tgt);

    float trans_acc = 0.0f, rot_acc = 0.0f;
    // Exactly 2 pairs per thread, straightline so loads can issue early.
    accum_pair(pbase + (size_t)tid * 3,             tbase + (size_t)tid * 3,             trans_acc, rot_acc);
    accum_pair(pbase + (size_t)(tid + NTHREAD) * 3, tbase + (size_t)(tid + NTHREAD) * 3, trans_acc, rot_acc);

    // Block reduction.
#pragma unroll
    for (int off = 32; off > 0; off >>= 1) {
        trans_acc += __shfl_down(trans_acc, off, 64);
        rot_acc   += __shfl_down(rot_acc,   off, 64);
    }
    __shared__ float sa[TPB / 64], sb[TPB / 64];
    __shared__ int   s_last;
    const int wid  = threadIdx.x >> 6;
    const int lane = threadIdx.x & 63;
    if (lane == 0) { sa[wid] = trans_acc; sb[wid] = rot_acc; }
    __syncthreads();
    if (threadIdx.x == 0) {
        float ta = 0.0f, tb = 0.0f;
#pragma unroll
        for (int w = 0; w < TPB / 64; ++w) { ta += sa[w]; tb += sb[w]; }
        // Agent-scope stores: per-XCD L2s aren't coherent; the finisher block may
        // be on a different XCD and may hold stale lines from a previous replay.
        __hip_atomic_store(&partial[blockIdx.x].x, ta, __ATOMIC_RELAXED, __HIP_MEMORY_SCOPE_AGENT);
        __hip_atomic_store(&partial[blockIdx.x].y, tb, __ATOMIC_RELAXED, __HIP_MEMORY_SCOPE_AGENT);
        unsigned int old = __hip_atomic_fetch_add(counter, 1u, __ATOMIC_ACQ_REL, __HIP_MEMORY_SCOPE_AGENT);
        s_last = (old == (unsigned int)(NBLK - 1)) ? 1 : 0;
    }
    __syncthreads();

    if (s_last) {
        // Last block: deterministic fixed-order reduction of all partials.
        float ta = 0.0f, tb = 0.0f;
        for (int i = threadIdx.x; i < NBLK; i += TPB) {
            ta += __hip_atomic_load(&partial[i].x, __ATOMIC_RELAXED, __HIP_MEMORY_SCOPE_AGENT);
            tb += __hip_atomic_load(&partial[i].y, __ATOMIC_RELAXED, __HIP_MEMORY_SCOPE_AGENT);
        }
#pragma unroll
        for (int off = 32; off > 0; off >>= 1) {
            ta += __shfl_down(ta, off, 64);
            tb += __shfl_down(tb, off, 64);
        }
        __syncthreads();   // reuse sa/sb safely
        if (lane == 0) { sa[wid] = ta; sb[wid] = tb; }
        __syncthreads();
        if (threadIdx.x == 0) {
            float st = 0.0f, sr = 0.0f;
#pragma unroll
            for (int w = 0; w < TPB / 64; ++w) { st += sa[w]; sr += sb[w]; }
            out[0] = st / (3.0f * (float)B_ROWS) + ANGLE_WEIGHT * (sr / (float)B_ROWS);
        }
    }
}

extern "C" void kernel_launch(void* const* d_in, const int* in_sizes, int n_in,
                              void* d_out, int out_size, void* d_ws, size_t ws_size,
                              hipStream_t stream) {
    const float* pred = (const float*)d_in[0];
    const float* tgt  = (const float*)d_in[1];
    float* out        = (float*)d_out;

    float2*       partial = (float2*)d_ws;                                   // 16 KB
    unsigned int* counter = (unsigned int*)((char*)d_ws + NBLK * sizeof(float2));

    hipMemsetAsync(counter, 0, sizeof(unsigned int), stream);
    rpmg_fused_kernel<<<NBLK, TPB, 0, stream>>>(pred, tgt, partial, counter, out);
}

// Round 4
// 44.688 us; speedup vs baseline: 3.0057x; 1.9463x over previous
//
#include <hip/hip_runtime.h>

// SimpleRPMGLoss: out = mean(smooth_l1(pred[:,:3], tgt[:,:3]))
//               + 100 * mean(acos(clip((sum(R(pred_e)*R(tgt_e)) - 1)/2)))
// B = 2,097,152 rows x 6 f32 each input. Memory-bound streaming reduction (~100 MB read).
//
// Fused single kernel, last-block-done finisher with NO cache-maintenance fences:
// ACQ_REL agent atomics emit buffer_wbl2/buffer_inv on gfx950 (per-XCD L2s are not
// coherent) -> 2048 L2 nukes mid-kernel made rounds 2-3 latency-bound (~440 GB/s).
// Instead: partials via relaxed agent-scope atomic stores (global_store sc1, write-
// through to coherence point) + s_waitcnt vmcnt(0) + relaxed agent fetch_add.
// Finisher reads partials via relaxed agent atomic loads (global_load sc1).

constexpr int   B_ROWS  = 2097152;
constexpr int   NBLK    = 2048;             // 8 blocks/CU on 256 CUs
constexpr int   TPB     = 256;
constexpr int   NTHREAD = NBLK * TPB;       // 524288 threads; 2 row-pairs each
constexpr int   NPAIRS  = B_ROWS / 2;       // 1048576
constexpr float ANGLE_WEIGHT = 100.0f;
constexpr float EPS_F        = 1e-7f;

typedef float f32x4 __attribute__((ext_vector_type(4)));

__device__ inline float smooth_l1_term(float d) {
    float ad = fabsf(d);
    return ad < 1.0f ? 0.5f * d * d : ad - 0.5f;
}

__device__ inline void euler_xyz_mat(float a, float b, float c, float r[9]) {
    float sa, ca, sb, cb, sc, cc;
    __sincosf(a, &sa, &ca);
    __sincosf(b, &sb, &cb);
    __sincosf(c, &sc, &cc);
    r[0] = cb * cc;
    r[1] = cc * sa * sb - ca * sc;
    r[2] = sc * sa + ca * cc * sb;
    r[3] = cb * sc;
    r[4] = ca * cc + sa * sb * sc;
    r[5] = ca * sb * sc - cc * sa;
    r[6] = -sb;
    r[7] = cb * sa;
    r[8] = ca * cb;
}

__device__ inline void accum_row(float px, float py, float pz,
                                 float pa, float pb, float pc,
                                 float tx, float ty, float tz,
                                 float ta, float tb, float tc,
                                 float& trans_acc, float& rot_acc) {
    trans_acc += smooth_l1_term(px - tx) + smooth_l1_term(py - ty) + smooth_l1_term(pz - tz);
    float rp[9], rt[9];
    euler_xyz_mat(pa, pb, pc, rp);
    euler_xyz_mat(ta, tb, tc, rt);
    float tr = 0.0f;
#pragma unroll
    for (int i = 0; i < 9; ++i) tr = fmaf(rp[i], rt[i], tr);
    float cosang = fminf(fmaxf((tr - 1.0f) * 0.5f, -1.0f + EPS_F), 1.0f - EPS_F);
    rot_acc += acosf(cosang);
}

__global__ __launch_bounds__(TPB) void rpmg_fused_kernel(const float* __restrict__ pred,
                                                         const float* __restrict__ tgt,
                                                         float2* __restrict__ partial,
                                                         unsigned int* __restrict__ counter,
                                                         float* __restrict__ out) {
    const int tid = blockIdx.x * TPB + threadIdx.x;

    float trans_acc = 0.0f, rot_acc = 0.0f;

    // Round-1-proven main loop: grid-stride over row-pairs (2 iterations).
    for (int p = tid; p < NPAIRS; p += NTHREAD) {
        const f32x4* pp = reinterpret_cast<const f32x4*>(pred + (size_t)p * 12);
        const f32x4* tp = reinterpret_cast<const f32x4*>(tgt  + (size_t)p * 12);
        f32x4 p0 = pp[0], p1 = pp[1], p2 = pp[2];
        f32x4 t0 = tp[0], t1 = tp[1], t2 = tp[2];
        accum_row(p0[0], p0[1], p0[2], p0[3], p1[0], p1[1],
                  t0[0], t0[1], t0[2], t0[3], t1[0], t1[1], trans_acc, rot_acc);
        accum_row(p1[2], p1[3], p2[0], p2[1], p2[2], p2[3],
                  t1[2], t1[3], t2[0], t2[1], t2[2], t2[3], trans_acc, rot_acc);
    }

    // Block reduction.
#pragma unroll
    for (int off = 32; off > 0; off >>= 1) {
        trans_acc += __shfl_down(trans_acc, off, 64);
        rot_acc   += __shfl_down(rot_acc,   off, 64);
    }
    __shared__ float sa[TPB / 64], sb[TPB / 64];
    __shared__ int   s_last;
    const int wid  = threadIdx.x >> 6;
    const int lane = threadIdx.x & 63;
    if (lane == 0) { sa[wid] = trans_acc; sb[wid] = rot_acc; }
    __syncthreads();
    if (threadIdx.x == 0) {
        float ta = 0.0f, tb = 0.0f;
#pragma unroll
        for (int w = 0; w < TPB / 64; ++w) { ta += sa[w]; tb += sb[w]; }
        // Write-through to the coherence point (sc1), no L2 writeback/invalidate.
        __hip_atomic_store(&partial[blockIdx.x].x, ta, __ATOMIC_RELAXED, __HIP_MEMORY_SCOPE_AGENT);
        __hip_atomic_store(&partial[blockIdx.x].y, tb, __ATOMIC_RELAXED, __HIP_MEMORY_SCOPE_AGENT);
        // Hand-rolled release: wait until those stores are acknowledged at the
        // coherence point, then bump the counter with a RELAXED RMW (no fences).
        asm volatile("s_waitcnt vmcnt(0)" ::: "memory");
        unsigned int old = __hip_atomic_fetch_add(counter, 1u, __ATOMIC_RELAXED, __HIP_MEMORY_SCOPE_AGENT);
        s_last = (old == (unsigned int)(NBLK - 1)) ? 1 : 0;
    }
    __syncthreads();

    if (s_last) {
        // Last block: fixed-order (deterministic) reduction of all partials.
        // Relaxed agent atomic loads bypass the (possibly stale) L1/L2.
        float ta = 0.0f, tb = 0.0f;
        for (int i = threadIdx.x; i < NBLK; i += TPB) {
            ta += __hip_atomic_load(&partial[i].x, __ATOMIC_RELAXED, __HIP_MEMORY_SCOPE_AGENT);
            tb += __hip_atomic_load(&partial[i].y, __ATOMIC_RELAXED, __HIP_MEMORY_SCOPE_AGENT);
        }
#pragma unroll
        for (int off = 32; off > 0; off >>= 1) {
            ta += __shfl_down(ta, off, 64);
            tb += __shfl_down(tb, off, 64);
        }
        __syncthreads();   // sa/sb reuse
        if (lane == 0) { sa[wid] = ta; sb[wid] = tb; }
        __syncthreads();
        if (threadIdx.x == 0) {
            float st = 0.0f, sr = 0.0f;
#pragma unroll
            for (int w = 0; w < TPB / 64; ++w) { st += sa[w]; sr += sb[w]; }
            out[0] = st / (3.0f * (float)B_ROWS) + ANGLE_WEIGHT * (sr / (float)B_ROWS);
        }
    }
}

extern "C" void kernel_launch(void* const* d_in, const int* in_sizes, int n_in,
                              void* d_out, int out_size, void* d_ws, size_t ws_size,
                              hipStream_t stream) {
    const float* pred = (const float*)d_in[0];
    const float* tgt  = (const float*)d_in[1];
    float* out        = (float*)d_out;

    float2*       partial = (float2*)d_ws;                                   // 16 KB
    unsigned int* counter = (unsigned int*)((char*)d_ws + NBLK * sizeof(float2));

    hipMemsetAsync(counter, 0, sizeof(unsigned int), stream);
    rpmg_fused_kernel<<<NBLK, TPB, 0, stream>>>(pred, tgt, partial, counter, out);
}

// Round 5
// 24.321 us; speedup vs baseline: 5.5226x; 1.8374x over previous
//
#include <hip/hip_runtime.h>

// SimpleRPMGLoss: out = mean(smooth_l1(pred[:,:3], tgt[:,:3]))
//               + 100 * mean(acos(clip((sum(R(pred_e)*R(tgt_e)) - 1)/2)))
// B = 2,097,152 rows x 6 f32 each input (~100 MB read). Memory-bound streaming reduction.
//
// Two-kernel structure (round-1-proven, no atomics, no memset):
//   k1: 2048 blocks x 256 thr, 2 row-pairs/thread, ALL 12 dwordx4 loads issued
//       straightline before compute (MLP), plain-store float2 partial per block.
//   k2: 1 block, fixed-order deterministic reduce of 2048 partials -> scalar.
// Fused last-block-done variants regressed: ACQ_REL agent RMW emits L2 wb/inv
// (114us), and even relaxed RMW left the kernel latency-bound at VGPR=32 (42us).

constexpr int   B_ROWS  = 2097152;
constexpr int   NBLK    = 2048;             // 8 blocks/CU on 256 CUs
constexpr int   TPB     = 256;
constexpr int   NTHREAD = NBLK * TPB;       // 524288 threads; 2 row-pairs each
constexpr float ANGLE_WEIGHT = 100.0f;
constexpr float EPS_F        = 1e-7f;

typedef float f32x4 __attribute__((ext_vector_type(4)));

__device__ inline float smooth_l1_term(float d) {
    float ad = fabsf(d);
    return ad < 1.0f ? 0.5f * d * d : ad - 0.5f;
}

__device__ inline void euler_xyz_mat(float a, float b, float c, float r[9]) {
    float sa, ca, sb, cb, sc, cc;
    __sincosf(a, &sa, &ca);
    __sincosf(b, &sb, &cb);
    __sincosf(c, &sc, &cc);
    r[0] = cb * cc;
    r[1] = cc * sa * sb - ca * sc;
    r[2] = sc * sa + ca * cc * sb;
    r[3] = cb * sc;
    r[4] = ca * cc + sa * sb * sc;
    r[5] = ca * sb * sc - cc * sa;
    r[6] = -sb;
    r[7] = cb * sa;
    r[8] = ca * cb;
}

__device__ inline void accum_row(float px, float py, float pz,
                                 float pa, float pb, float pc,
                                 float tx, float ty, float tz,
                                 float ta, float tb, float tc,
                                 float& trans_acc, float& rot_acc) {
    trans_acc += smooth_l1_term(px - tx) + smooth_l1_term(py - ty) + smooth_l1_term(pz - tz);
    float rp[9], rt[9];
    euler_xyz_mat(pa, pb, pc, rp);
    euler_xyz_mat(ta, tb, tc, rt);
    float tr = 0.0f;
#pragma unroll
    for (int i = 0; i < 9; ++i) tr = fmaf(rp[i], rt[i], tr);
    float cosang = fminf(fmaxf((tr - 1.0f) * 0.5f, -1.0f + EPS_F), 1.0f - EPS_F);
    rot_acc += acosf(cosang);
}

// min 4 waves/EU -> VGPR budget 128: room to keep all 12 dwordx4 results live.
__global__ __launch_bounds__(TPB, 4) void rpmg_partial_kernel(const float* __restrict__ pred,
                                                              const float* __restrict__ tgt,
                                                              float2* __restrict__ partial) {
    const int tid = blockIdx.x * TPB + threadIdx.x;
    const f32x4* pp1 = reinterpret_cast<const f32x4*>(pred) + (size_t)tid * 3;
    const f32x4* tp1 = reinterpret_cast<const f32x4*>(tgt)  + (size_t)tid * 3;
    const f32x4* pp2 = pp1 + (size_t)NTHREAD * 3;
    const f32x4* tp2 = tp1 + (size_t)NTHREAD * 3;

    // Issue ALL loads up front (4 address pairs + imm offsets; 48 data VGPRs).
    f32x4 a0 = pp1[0], a1 = pp1[1], a2 = pp1[2];
    f32x4 b0 = tp1[0], b1 = tp1[1], b2 = tp1[2];
    f32x4 c0 = pp2[0], c1 = pp2[1], c2 = pp2[2];
    f32x4 d0 = tp2[0], d1 = tp2[1], d2 = tp2[2];

    float trans_acc = 0.0f, rot_acc = 0.0f;
    accum_row(a0[0], a0[1], a0[2], a0[3], a1[0], a1[1],
              b0[0], b0[1], b0[2], b0[3], b1[0], b1[1], trans_acc, rot_acc);
    accum_row(a1[2], a1[3], a2[0], a2[1], a2[2], a2[3],
              b1[2], b1[3], b2[0], b2[1], b2[2], b2[3], trans_acc, rot_acc);
    accum_row(c0[0], c0[1], c0[2], c0[3], c1[0], c1[1],
              d0[0], d0[1], d0[2], d0[3], d1[0], d1[1], trans_acc, rot_acc);
    accum_row(c1[2], c1[3], c2[0], c2[1], c2[2], c2[3],
              d1[2], d1[3], d2[0], d2[1], d2[2], d2[3], trans_acc, rot_acc);

    // Block reduction -> one float2 per block (plain store; dispatch-boundary
    // release/acquire makes it visible to kernel 2).
#pragma unroll
    for (int off = 32; off > 0; off >>= 1) {
        trans_acc += __shfl_down(trans_acc, off, 64);
        rot_acc   += __shfl_down(rot_acc,   off, 64);
    }
    __shared__ float sa[TPB / 64], sb[TPB / 64];
    const int wid  = threadIdx.x >> 6;
    const int lane = threadIdx.x & 63;
    if (lane == 0) { sa[wid] = trans_acc; sb[wid] = rot_acc; }
    __syncthreads();
    if (threadIdx.x == 0) {
        float ta = 0.0f, tb = 0.0f;
#pragma unroll
        for (int w = 0; w < TPB / 64; ++w) { ta += sa[w]; tb += sb[w]; }
        partial[blockIdx.x] = make_float2(ta, tb);
    }
}

__global__ __launch_bounds__(TPB) void rpmg_final_kernel(const float2* __restrict__ partial,
                                                         float* __restrict__ out) {
    float ta = 0.0f, tb = 0.0f;
    for (int i = threadIdx.x; i < NBLK; i += TPB) {
        float2 v = partial[i];
        ta += v.x;
        tb += v.y;
    }
#pragma unroll
    for (int off = 32; off > 0; off >>= 1) {
        ta += __shfl_down(ta, off, 64);
        tb += __shfl_down(tb, off, 64);
    }
    __shared__ float sa[TPB / 64], sb[TPB / 64];
    const int wid  = threadIdx.x >> 6;
    const int lane = threadIdx.x & 63;
    if (lane == 0) { sa[wid] = ta; sb[wid] = tb; }
    __syncthreads();
    if (threadIdx.x == 0) {
        float st = 0.0f, sr = 0.0f;
#pragma unroll
        for (int w = 0; w < TPB / 64; ++w) { st += sa[w]; sr += sb[w]; }
        out[0] = st / (3.0f * (float)B_ROWS) + ANGLE_WEIGHT * (sr / (float)B_ROWS);
    }
}

extern "C" void kernel_launch(void* const* d_in, const int* in_sizes, int n_in,
                              void* d_out, int out_size, void* d_ws, size_t ws_size,
                              hipStream_t stream) {
    const float* pred = (const float*)d_in[0];
    const float* tgt  = (const float*)d_in[1];
    float* out        = (float*)d_out;
    float2* partial   = (float2*)d_ws;      // 16 KB scratch

    rpmg_partial_kernel<<<NBLK, TPB, 0, stream>>>(pred, tgt, partial);
    rpmg_final_kernel<<<1, TPB, 0, stream>>>(partial, out);
}